// Round 9
// baseline (499.877 us; speedup 1.0000x reference)
//
#include <hip/hip_runtime.h>
#include <hip/hip_bf16.h>
#include <stdint.h>

#define NE 8
#define T_TOK 4096
#define H_DIM 1024
#define I_DIM 4096
#define CAP 4096
#define RB128 72  // max total 128-row blocks: 8192/128 + 8 = 72

typedef __attribute__((ext_vector_type(8))) short bf16x8;
typedef __attribute__((ext_vector_type(4))) float f32x4;
typedef __attribute__((ext_vector_type(8))) unsigned short u16x8;

#define VMCNT0 asm volatile("s_waitcnt vmcnt(0)" ::: "memory")

__device__ __forceinline__ unsigned short f2bf(float f) {
  __hip_bfloat16 h = __float2bfloat16(f);
  return *reinterpret_cast<unsigned short*>(&h);
}

__device__ __forceinline__ void lds_load16(const void* g, void* l) {
  __builtin_amdgcn_global_load_lds((__attribute__((address_space(1))) void*)g,
                                   (__attribute__((address_space(3))) void*)l,
                                   16, 0, 0);
}

// swizzled LDS fragment read: tile layout [rows][64 bf16] (128B rows, 8x16B
// chunks); content chunk cc of row lives at physical chunk cc ^ (row&7)
__device__ __forceinline__ const bf16x8* lds_frag(const char* base, int row,
                                                  int cc) {
  return (const bf16x8*)(base + row * 128 + ((cc ^ (row & 7)) << 4));
}

// bijective XCD swizzle (nwg % 8 == 0): each XCD owns a contiguous logical chunk
__device__ __forceinline__ int xcd_swz(int bid, int nwg) {
  return (bid & 7) * (nwg >> 3) + (bid >> 3);
}

// map flat 128-row block g -> (expert e, local block mb); rowbase is 128*g
__device__ __forceinline__ bool rb_lookup(const int* counts, int g, int* e_out,
                                          int* mb_out, int* cnt_out) {
  int acc = 0;
#pragma unroll
  for (int i = 0; i < NE; ++i) {
    int c = counts[i];
    int rb = (c + 127) >> 7;
    if (g < acc + rb) {
      *e_out = i;
      *mb_out = g - acc;
      *cnt_out = c;
      return true;
    }
    acc += rb;
  }
  return false;
}

// ---------------- router: 1 wave per token ----------------
__global__ void router_kernel(const float* __restrict__ x,
                              const float* __restrict__ rw,
                              int* __restrict__ counts,
                              int* __restrict__ perm,
                              int* __restrict__ se,
                              float* __restrict__ wtok) {
  const int t = blockIdx.x;
  const int lane = threadIdx.x;  // 64 threads
  float acc[NE];
#pragma unroll
  for (int e = 0; e < NE; ++e) acc[e] = 0.f;
  const float* xr = x + (size_t)t * H_DIM;
#pragma unroll
  for (int it = 0; it < H_DIM / 64; ++it) {
    int d = it * 64 + lane;
    float xv = xr[d];
#pragma unroll
    for (int e = 0; e < NE; ++e) acc[e] += xv * rw[e * H_DIM + d];
  }
#pragma unroll
  for (int e = 0; e < NE; ++e) {
#pragma unroll
    for (int off = 32; off > 0; off >>= 1) acc[e] += __shfl_xor(acc[e], off);
  }
  if (lane == 0) {
    int i0 = 0;
#pragma unroll
    for (int e = 1; e < NE; ++e)
      if (acc[e] > acc[i0]) i0 = e;
    int i1 = (i0 == 0) ? 1 : 0;
#pragma unroll
    for (int e = 0; e < NE; ++e)
      if (e != i0 && acc[e] > acc[i1]) i1 = e;
    float la = acc[i0], lb = acc[i1];
    float r = expf(lb - la);          // <= 1
    float wa = 1.f / (1.f + r);       // normalized top-2 softmax weights
    float wb = 1.f - wa;
    int p0 = atomicAdd(&counts[i0], 1);
    perm[i0 * CAP + p0] = t;
    se[2 * t + 0] = (i0 << 20) | p0;
    wtok[2 * t + 0] = wa;
    int p1 = atomicAdd(&counts[i1], 1);
    perm[i1 * CAP + p1] = t;
    se[2 * t + 1] = (i1 << 20) | p1;
    wtok[2 * t + 1] = wb;
  }
}

// ---------------- x -> bf16 ----------------
__global__ void convert_x_kernel(const float* __restrict__ x,
                                 unsigned short* __restrict__ xb) {
  int i = blockIdx.x * blockDim.x + threadIdx.x;  // one float4 each
  float4 v = reinterpret_cast<const float4*>(x)[i];
  ushort4 o;
  o.x = f2bf(v.x); o.y = f2bf(v.y); o.z = f2bf(v.z); o.w = f2bf(v.w);
  reinterpret_cast<ushort4*>(xb)[i] = o;
}

// ---------------- transpose + convert: src [E][R][C] f32 -> dst [E][C][R] bf16
__global__ void __launch_bounds__(256) transpose_conv_kernel(
    const float* __restrict__ src, unsigned short* __restrict__ dst,
    int R, int C) {
  __shared__ float tile[64][65];
  const int e = blockIdx.z;
  const int c0 = blockIdx.x * 64, r0 = blockIdx.y * 64;
  const float* s = src + (size_t)e * R * C;
  unsigned short* d = dst + (size_t)e * R * C;
  const int tid = threadIdx.x;
  const int lr = tid >> 4, lc = (tid & 15) << 2;
#pragma unroll
  for (int j = 0; j < 4; ++j) {
    float4 v = *reinterpret_cast<const float4*>(
        &s[(size_t)(r0 + j * 16 + lr) * C + c0 + lc]);
    tile[j * 16 + lr][lc + 0] = v.x;
    tile[j * 16 + lr][lc + 1] = v.y;
    tile[j * 16 + lr][lc + 2] = v.z;
    tile[j * 16 + lr][lc + 3] = v.w;
  }
  __syncthreads();
  const int oc = tid >> 3, orr = (tid & 7) << 3;
#pragma unroll
  for (int j = 0; j < 2; ++j) {
    int c = j * 32 + oc;
    u16x8 o;
#pragma unroll
    for (int k = 0; k < 8; ++k) o[k] = f2bf(tile[orr + k][c]);
    *reinterpret_cast<u16x8*>(&d[(size_t)(c0 + c) * R + r0 + orr]) = o;
  }
}

// ---------------- FFN1: inter = gelu(X[perm] @ w_in + b_in), bf16 out --------
// m97 structure: 128x128 tile, BK=64, 256 thr (4 waves 2x2, 64x64/wave),
// single-buffer 32KB LDS, 2-barrier loop (multi-block/CU residency hides the
// barrier drain). T2 chunk-swizzle. Compact grid 32nb * RB128, nb-major.
// Epilogue: barrier-synced LDS coalescing (16B/lane stores).
__global__ void __launch_bounds__(256) ffn1_kernel(
    const unsigned short* __restrict__ xb,
    const unsigned short* __restrict__ win_t,  // [E][I][H]
    const float* __restrict__ b_in,            // [E][I]
    const int* __restrict__ counts,
    const int* __restrict__ perm,
    unsigned short* __restrict__ inter) {
  const int logical = xcd_swz(blockIdx.x, 32 * RB128);
  const int nb = logical / RB128;  // 0..31, consecutive logicals share B panel
  const int g = logical % RB128;
  int e, mb, cnt;
  if (!rb_lookup(counts, g, &e, &mb, &cnt)) return;

  __shared__ char smem[32768];  // A 16KB | B 16KB (epilogue: 4 x 8KB slices)

  const int tid = threadIdx.x;
  int tokr[4];
#pragma unroll
  for (int it = 0; it < 4; ++it) {
    int r = (it * 256 + tid) >> 3;  // 0..127
    tokr[it] = perm[e * CAP + min(mb * 128 + r, cnt - 1)];
  }

  const int wave = tid >> 6, lane = tid & 63;
  const int wr = wave >> 1, wn = wave & 1;  // 2M x 2N
  const int l16 = lane & 15, l4 = lane >> 4;
  const unsigned short* Bbase =
      win_t + (size_t)e * I_DIM * H_DIM + (size_t)(nb * 128) * H_DIM;

  f32x4 acc[4][4] = {};

  const int NK = H_DIM / 64;  // 16
  for (int kt = 0; kt < NK; ++kt) {
    __syncthreads();  // all waves done reading smem (prev iter)
#pragma unroll
    for (int it = 0; it < 4; ++it) {
      int id = it * 256 + tid;
      int r = id >> 3;
      int cs = (id & 7) ^ (r & 7);  // T2: pre-swizzled source chunk
      lds_load16(xb + (size_t)tokr[it] * H_DIM + kt * 64 + cs * 8,
                 smem + id * 16);
      lds_load16(Bbase + (size_t)r * H_DIM + kt * 64 + cs * 8,
                 smem + 16384 + id * 16);
    }
    VMCNT0;  // explicit: all LDS-DMA for this tile landed
    __syncthreads();
#pragma unroll
    for (int kk = 0; kk < 2; ++kk) {
      bf16x8 af[4], bv[4];
#pragma unroll
      for (int m = 0; m < 4; ++m)
        af[m] = *lds_frag(smem, wr * 64 + m * 16 + l16, kk * 4 + l4);
#pragma unroll
      for (int n = 0; n < 4; ++n)
        bv[n] = *lds_frag(smem + 16384, wn * 64 + n * 16 + l16, kk * 4 + l4);
#pragma unroll
      for (int m = 0; m < 4; ++m)
#pragma unroll
        for (int n = 0; n < 4; ++n)
          acc[m][n] =
              __builtin_amdgcn_mfma_f32_16x16x32_bf16(af[m], bv[n], acc[m][n], 0, 0, 0);
    }
  }

  // ---- epilogue: GELU, coalesce via per-wave 8KB LDS slice ----
  __syncthreads();  // all waves done with staging LDS
  const size_t rowbase = (size_t)g * 128;
  unsigned short* slice = (unsigned short*)(smem + wave * 8192);
#pragma unroll
  for (int n = 0; n < 4; ++n) {
    float bias = b_in[e * I_DIM + nb * 128 + wn * 64 + n * 16 + l16];
#pragma unroll
    for (int m = 0; m < 4; ++m) {
#pragma unroll
      for (int j = 0; j < 4; ++j) {
        float v = acc[m][n][j] + bias;
        // tanh-form GELU: v * sigmoid(1.59577(v + 0.044715 v^3)); |err| <~1e-3
        float t = __expf(-1.5957691216057308f * v - 0.07135481627f * v * v * v);
        float gg = v / (1.f + t);
        slice[(m * 16 + l4 * 4 + j) * 64 + n * 16 + l16] = f2bf(gg);
      }
    }
  }
  __syncthreads();  // slice writes visible before cross-lane readback
#pragma unroll
  for (int it = 0; it < 8; ++it) {
    int row = it * 8 + (lane >> 3);        // 0..63
    int colb = (lane & 7) * 8;             // 8 bf16 = 16B
    u16x8 v = *(const u16x8*)&slice[row * 64 + colb];
    *(u16x8*)&inter[(rowbase + wr * 64 + row) * (size_t)I_DIM + nb * 128 +
                    wn * 64 + colb] = v;
  }
}

// ---------------- FFN2: y[slot] = inter @ w_out + b_out (dense, no atomics) --
// m97 structure, 128x128 tile. A-MAJOR grid (g-major): the 8 nb-blocks sharing
// one A-panel co-reside per XCD (keeps the FETCH win). grid 576, ~528 active.
__global__ void __launch_bounds__(256) ffn2_kernel(
    const unsigned short* __restrict__ inter,
    const unsigned short* __restrict__ wout_t,  // [E][H][I]
    const float* __restrict__ b_out,            // [E][H]
    const int* __restrict__ counts,
    float* __restrict__ y) {                    // [slot][H]
  const int logical = xcd_swz(blockIdx.x, RB128 * 8);
  const int g = logical >> 3;      // consecutive logicals share A panel
  const int nb = logical & 7;
  int e, mb, cnt;
  if (!rb_lookup(counts, g, &e, &mb, &cnt)) return;
  (void)mb;

  __shared__ char smem[32768];  // A 16KB | B 16KB

  const int tid = threadIdx.x;
  const int wave = tid >> 6, lane = tid & 63;
  const int wr = wave >> 1, wn = wave & 1;  // 2M x 2N
  const int l16 = lane & 15, l4 = lane >> 4;
  const unsigned short* Bbase =
      wout_t + (size_t)e * H_DIM * I_DIM + (size_t)(nb * 128) * I_DIM;
  const size_t rowbase = (size_t)g * 128;

  f32x4 acc[4][4] = {};

  const int NK = I_DIM / 64;  // 64
  for (int kt = 0; kt < NK; ++kt) {
    __syncthreads();
#pragma unroll
    for (int it = 0; it < 4; ++it) {
      int id = it * 256 + tid;
      int r = id >> 3;
      int cs = (id & 7) ^ (r & 7);
      lds_load16(inter + (rowbase + r) * (size_t)I_DIM + kt * 64 + cs * 8,
                 smem + id * 16);
      lds_load16(Bbase + (size_t)r * I_DIM + kt * 64 + cs * 8,
                 smem + 16384 + id * 16);
    }
    VMCNT0;
    __syncthreads();
#pragma unroll
    for (int kk = 0; kk < 2; ++kk) {
      bf16x8 af[4], bv[4];
#pragma unroll
      for (int m = 0; m < 4; ++m)
        af[m] = *lds_frag(smem, wr * 64 + m * 16 + l16, kk * 4 + l4);
#pragma unroll
      for (int n = 0; n < 4; ++n)
        bv[n] = *lds_frag(smem + 16384, wn * 64 + n * 16 + l16, kk * 4 + l4);
#pragma unroll
      for (int m = 0; m < 4; ++m)
#pragma unroll
        for (int n = 0; n < 4; ++n)
          acc[m][n] =
              __builtin_amdgcn_mfma_f32_16x16x32_bf16(af[m], bv[n], acc[m][n], 0, 0, 0);
    }
  }

  // ---- epilogue: two 32-row passes through per-wave 8KB LDS slice ----
  __syncthreads();
  float* slice = (float*)(smem + wave * 8192);
  float bias[4];
#pragma unroll
  for (int n = 0; n < 4; ++n)
    bias[n] = b_out[e * H_DIM + nb * 128 + wn * 64 + n * 16 + l16];
#pragma unroll
  for (int p = 0; p < 2; ++p) {
#pragma unroll
    for (int mm = 0; mm < 2; ++mm) {
      int m = p * 2 + mm;
#pragma unroll
      for (int n = 0; n < 4; ++n) {
#pragma unroll
        for (int j = 0; j < 4; ++j) {
          slice[(mm * 16 + l4 * 4 + j) * 64 + n * 16 + l16] =
              acc[m][n][j] + bias[n];
        }
      }
    }
    __syncthreads();  // slice writes visible before cross-lane readback
#pragma unroll
    for (int it = 0; it < 8; ++it) {
      int row = it * 4 + (lane >> 4);      // 0..31
      int col = (lane & 15) * 4;           // 4 floats = 16B
      float4 v = *(const float4*)&slice[row * 64 + col];
      *(float4*)&y[(rowbase + wr * 64 + p * 32 + row) * (size_t)H_DIM +
                   nb * 128 + wn * 64 + col] = v;
    }
    __syncthreads();  // readback done before next pass overwrites slice
  }
}

// ---------------- combine: out[t] = w0*y[slot0] + w1*y[slot1] ---------------
__global__ void __launch_bounds__(256) combine_kernel(
    const float* __restrict__ y, const int* __restrict__ counts,
    const int* __restrict__ se, const float* __restrict__ wtok,
    float* __restrict__ out) {
  const int t = blockIdx.x;
  int poff[NE];
  int run = 0;
#pragma unroll
  for (int e = 0; e < NE; ++e) {
    poff[e] = run;
    run += (counts[e] + 127) & ~127;  // must match 128-row block padding
  }
  int c0 = se[2 * t], c1 = se[2 * t + 1];
  float w0 = wtok[2 * t], w1 = wtok[2 * t + 1];
  const float* y0 = y + (size_t)(poff[c0 >> 20] + (c0 & 0xFFFFF)) * H_DIM;
  const float* y1 = y + (size_t)(poff[c1 >> 20] + (c1 & 0xFFFFF)) * H_DIM;
  int h = threadIdx.x * 4;
  float4 a = *reinterpret_cast<const float4*>(y0 + h);
  float4 b = *reinterpret_cast<const float4*>(y1 + h);
  float4 o;
  o.x = w0 * a.x + w1 * b.x;
  o.y = w0 * a.y + w1 * b.y;
  o.z = w0 * a.z + w1 * b.z;
  o.w = w0 * a.w + w1 * b.w;
  *reinterpret_cast<float4*>(out + (size_t)t * H_DIM + h) = o;
}

extern "C" void kernel_launch(void* const* d_in, const int* in_sizes, int n_in,
                              void* d_out, int out_size, void* d_ws, size_t ws_size,
                              hipStream_t stream) {
  const float* x     = (const float*)d_in[0];
  const float* rw    = (const float*)d_in[1];
  const float* w_in  = (const float*)d_in[2];
  const float* b_in  = (const float*)d_in[3];
  const float* w_out = (const float*)d_in[4];
  const float* b_out = (const float*)d_in[5];
  float* out = (float*)d_out;

  char* ws = (char*)d_ws;
  size_t off = 0;
  auto alloc = [&](size_t bytes) {
    char* p = ws + off;
    off = (off + bytes + 255) & ~(size_t)255;
    return p;
  };
  int* counts            = (int*)alloc(NE * 4);
  int* perm              = (int*)alloc((size_t)NE * CAP * 4);
  int* se                = (int*)alloc((size_t)T_TOK * 2 * 4);
  float* wtok            = (float*)alloc((size_t)T_TOK * 2 * 4);
  unsigned short* xb     = (unsigned short*)alloc((size_t)T_TOK * H_DIM * 2);
  unsigned short* win_t  = (unsigned short*)alloc((size_t)NE * H_DIM * I_DIM * 2);
  unsigned short* wout_t = (unsigned short*)alloc((size_t)NE * H_DIM * I_DIM * 2);
  unsigned short* inter  = (unsigned short*)alloc((size_t)(T_TOK * 2 + NE * 256) * I_DIM * 2);
  // y overlays ONLY win_t (dead after ffn1; rewritten by transpose before the
  // next ffn1): need <= 9216*1024*4 = 37.7MB <= 64MB
  float* y = (float*)win_t;
  if (off > ws_size) return;  // ws too small -> visible correctness failure

  hipMemsetAsync(counts, 0, NE * sizeof(int), stream);

  router_kernel<<<T_TOK, 64, 0, stream>>>(x, rw, counts, perm, se, wtok);
  convert_x_kernel<<<(T_TOK * H_DIM / 4) / 256, 256, 0, stream>>>(x, xb);
  transpose_conv_kernel<<<dim3(I_DIM / 64, H_DIM / 64, NE), 256, 0, stream>>>(
      w_in, win_t, H_DIM, I_DIM);
  transpose_conv_kernel<<<dim3(H_DIM / 64, I_DIM / 64, NE), 256, 0, stream>>>(
      w_out, wout_t, I_DIM, H_DIM);
  ffn1_kernel<<<32 * RB128, 256, 0, stream>>>(xb, win_t, b_in, counts, perm,
                                              inter);
  ffn2_kernel<<<RB128 * 8, 256, 0, stream>>>(inter, wout_t, b_out, counts, y);
  combine_kernel<<<T_TOK, 256, 0, stream>>>(y, counts, se, wtok, out);
}

// Round 10
// 386.883 us; speedup vs baseline: 1.2921x; 1.2921x over previous
//
#include <hip/hip_runtime.h>
#include <hip/hip_bf16.h>
#include <stdint.h>

#define NE 8
#define T_TOK 4096
#define H_DIM 1024
#define I_DIM 4096
#define CAP 4096
#define RB128 72  // max total 128-row blocks: 8192/128 + 8 = 72

typedef __attribute__((ext_vector_type(8))) short bf16x8;
typedef __attribute__((ext_vector_type(4))) float f32x4;
typedef __attribute__((ext_vector_type(8))) unsigned short u16x8;

__device__ __forceinline__ unsigned short f2bf(float f) {
  __hip_bfloat16 h = __float2bfloat16(f);
  return *reinterpret_cast<unsigned short*>(&h);
}

__device__ __forceinline__ void lds_load16(const void* g, void* l) {
  __builtin_amdgcn_global_load_lds((__attribute__((address_space(1))) void*)g,
                                   (__attribute__((address_space(3))) void*)l,
                                   16, 0, 0);
}

// swizzled LDS fragment read: tile layout [rows][64 bf16] (128B rows, 8x16B
// chunks); content chunk cc of row lives at physical chunk cc ^ (row&7)
__device__ __forceinline__ const bf16x8* lds_frag(const char* base, int row,
                                                  int cc) {
  return (const bf16x8*)(base + row * 128 + ((cc ^ (row & 7)) << 4));
}

// bijective XCD swizzle (nwg % 8 == 0): each XCD owns a contiguous logical chunk
__device__ __forceinline__ int xcd_swz(int bid, int nwg) {
  return (bid & 7) * (nwg >> 3) + (bid >> 3);
}

// map flat 128-row block g -> (expert e, local block mb); rowbase is 128*g
__device__ __forceinline__ bool rb_lookup(const int* counts, int g, int* e_out,
                                          int* mb_out, int* cnt_out) {
  int acc = 0;
#pragma unroll
  for (int i = 0; i < NE; ++i) {
    int c = counts[i];
    int rb = (c + 127) >> 7;
    if (g < acc + rb) {
      *e_out = i;
      *mb_out = g - acc;
      *cnt_out = c;
      return true;
    }
    acc += rb;
  }
  return false;
}

// ---------------- router: 1 wave per token ----------------
__global__ void router_kernel(const float* __restrict__ x,
                              const float* __restrict__ rw,
                              int* __restrict__ counts,
                              int* __restrict__ perm,
                              int* __restrict__ se,
                              float* __restrict__ wtok) {
  const int t = blockIdx.x;
  const int lane = threadIdx.x;  // 64 threads
  float acc[NE];
#pragma unroll
  for (int e = 0; e < NE; ++e) acc[e] = 0.f;
  const float* xr = x + (size_t)t * H_DIM;
#pragma unroll
  for (int it = 0; it < H_DIM / 64; ++it) {
    int d = it * 64 + lane;
    float xv = xr[d];
#pragma unroll
    for (int e = 0; e < NE; ++e) acc[e] += xv * rw[e * H_DIM + d];
  }
#pragma unroll
  for (int e = 0; e < NE; ++e) {
#pragma unroll
    for (int off = 32; off > 0; off >>= 1) acc[e] += __shfl_xor(acc[e], off);
  }
  if (lane == 0) {
    int i0 = 0;
#pragma unroll
    for (int e = 1; e < NE; ++e)
      if (acc[e] > acc[i0]) i0 = e;
    int i1 = (i0 == 0) ? 1 : 0;
#pragma unroll
    for (int e = 0; e < NE; ++e)
      if (e != i0 && acc[e] > acc[i1]) i1 = e;
    float la = acc[i0], lb = acc[i1];
    float r = expf(lb - la);          // <= 1
    float wa = 1.f / (1.f + r);       // normalized top-2 softmax weights
    float wb = 1.f - wa;
    int p0 = atomicAdd(&counts[i0], 1);
    perm[i0 * CAP + p0] = t;
    se[2 * t + 0] = (i0 << 20) | p0;
    wtok[2 * t + 0] = wa;
    int p1 = atomicAdd(&counts[i1], 1);
    perm[i1 * CAP + p1] = t;
    se[2 * t + 1] = (i1 << 20) | p1;
    wtok[2 * t + 1] = wb;
  }
}

// ---------------- x -> bf16 ----------------
__global__ void convert_x_kernel(const float* __restrict__ x,
                                 unsigned short* __restrict__ xb) {
  int i = blockIdx.x * blockDim.x + threadIdx.x;  // one float4 each
  float4 v = reinterpret_cast<const float4*>(x)[i];
  ushort4 o;
  o.x = f2bf(v.x); o.y = f2bf(v.y); o.z = f2bf(v.z); o.w = f2bf(v.w);
  reinterpret_cast<ushort4*>(xb)[i] = o;
}

// ---------------- transpose + convert: src [E][R][C] f32 -> dst [E][C][R] bf16
__global__ void __launch_bounds__(256) transpose_conv_kernel(
    const float* __restrict__ src, unsigned short* __restrict__ dst,
    int R, int C) {
  __shared__ float tile[64][65];
  const int e = blockIdx.z;
  const int c0 = blockIdx.x * 64, r0 = blockIdx.y * 64;
  const float* s = src + (size_t)e * R * C;
  unsigned short* d = dst + (size_t)e * R * C;
  const int tid = threadIdx.x;
  const int lr = tid >> 4, lc = (tid & 15) << 2;
#pragma unroll
  for (int j = 0; j < 4; ++j) {
    float4 v = *reinterpret_cast<const float4*>(
        &s[(size_t)(r0 + j * 16 + lr) * C + c0 + lc]);
    tile[j * 16 + lr][lc + 0] = v.x;
    tile[j * 16 + lr][lc + 1] = v.y;
    tile[j * 16 + lr][lc + 2] = v.z;
    tile[j * 16 + lr][lc + 3] = v.w;
  }
  __syncthreads();
  const int oc = tid >> 3, orr = (tid & 7) << 3;
#pragma unroll
  for (int j = 0; j < 2; ++j) {
    int c = j * 32 + oc;
    u16x8 o;
#pragma unroll
    for (int k = 0; k < 8; ++k) o[k] = f2bf(tile[orr + k][c]);
    *reinterpret_cast<u16x8*>(&d[(size_t)(c0 + c) * R + r0 + orr]) = o;
  }
}

// ---------------- FFN1: inter = gelu(X[perm] @ w_in + b_in), bf16 out --------
// m97 structure: 128x128 tile, BK=64, 256 thr (4 waves 2x2, 64x64/wave),
// single-buffer 32KB LDS, 2-barrier loop (multi-block/CU residency hides the
// barrier drain; compiler emits the vmcnt drain at s_barrier itself).
// T2 chunk-swizzle. Compact grid 32nb * RB128, nb-major.
__global__ void __launch_bounds__(256, 3) ffn1_kernel(
    const unsigned short* __restrict__ xb,
    const unsigned short* __restrict__ win_t,  // [E][I][H]
    const float* __restrict__ b_in,            // [E][I]
    const int* __restrict__ counts,
    const int* __restrict__ perm,
    unsigned short* __restrict__ inter) {
  const int logical = xcd_swz(blockIdx.x, 32 * RB128);
  const int nb = logical / RB128;  // 0..31, consecutive logicals share B panel
  const int g = logical % RB128;
  int e, mb, cnt;
  if (!rb_lookup(counts, g, &e, &mb, &cnt)) return;

  __shared__ char smem[32768];  // A 16KB | B 16KB (epilogue: 4 x 8KB slices)

  const int tid = threadIdx.x;
  int tokr[4];
#pragma unroll
  for (int it = 0; it < 4; ++it) {
    int r = (it * 256 + tid) >> 3;  // 0..127
    tokr[it] = perm[e * CAP + min(mb * 128 + r, cnt - 1)];
  }

  const int wave = tid >> 6, lane = tid & 63;
  const int wr = wave >> 1, wn = wave & 1;  // 2M x 2N
  const int l16 = lane & 15, l4 = lane >> 4;
  const unsigned short* Bbase =
      win_t + (size_t)e * I_DIM * H_DIM + (size_t)(nb * 128) * H_DIM;

  f32x4 acc[4][4] = {};

  const int NK = H_DIM / 64;  // 16
  for (int kt = 0; kt < NK; ++kt) {
    __syncthreads();  // all waves done reading smem (prev iter)
#pragma unroll
    for (int it = 0; it < 4; ++it) {
      int id = it * 256 + tid;
      int r = id >> 3;
      int cs = (id & 7) ^ (r & 7);  // T2: pre-swizzled source chunk
      lds_load16(xb + (size_t)tokr[it] * H_DIM + kt * 64 + cs * 8,
                 smem + id * 16);
      lds_load16(Bbase + (size_t)r * H_DIM + kt * 64 + cs * 8,
                 smem + 16384 + id * 16);
    }
    __syncthreads();  // compiler drains vmcnt(0) here (m97 asm behavior)
#pragma unroll
    for (int kk = 0; kk < 2; ++kk) {
      bf16x8 af[4], bv[4];
#pragma unroll
      for (int m = 0; m < 4; ++m)
        af[m] = *lds_frag(smem, wr * 64 + m * 16 + l16, kk * 4 + l4);
#pragma unroll
      for (int n = 0; n < 4; ++n)
        bv[n] = *lds_frag(smem + 16384, wn * 64 + n * 16 + l16, kk * 4 + l4);
#pragma unroll
      for (int m = 0; m < 4; ++m)
#pragma unroll
        for (int n = 0; n < 4; ++n)
          acc[m][n] =
              __builtin_amdgcn_mfma_f32_16x16x32_bf16(af[m], bv[n], acc[m][n], 0, 0, 0);
    }
  }

  // ---- epilogue: GELU, coalesce via per-wave 8KB LDS slice ----
  __syncthreads();  // all waves done with staging LDS
  const size_t rowbase = (size_t)g * 128;
  unsigned short* slice = (unsigned short*)(smem + wave * 8192);
#pragma unroll
  for (int n = 0; n < 4; ++n) {
    float bias = b_in[e * I_DIM + nb * 128 + wn * 64 + n * 16 + l16];
#pragma unroll
    for (int m = 0; m < 4; ++m) {
#pragma unroll
      for (int j = 0; j < 4; ++j) {
        float v = acc[m][n][j] + bias;
        // tanh-form GELU: v * sigmoid(1.59577(v + 0.044715 v^3)); |err| <~1e-3
        float t = __expf(-1.5957691216057308f * v - 0.07135481627f * v * v * v);
        float gg = v / (1.f + t);
        slice[(m * 16 + l4 * 4 + j) * 64 + n * 16 + l16] = f2bf(gg);
      }
    }
  }
  __syncthreads();  // slice writes visible before cross-lane readback
#pragma unroll
  for (int it = 0; it < 8; ++it) {
    int row = it * 8 + (lane >> 3);        // 0..63
    int colb = (lane & 7) * 8;             // 8 bf16 = 16B
    u16x8 v = *(const u16x8*)&slice[row * 64 + colb];
    *(u16x8*)&inter[(rowbase + wr * 64 + row) * (size_t)I_DIM + nb * 128 +
                    wn * 64 + colb] = v;
  }
}

// ---------------- FFN2: y[slot] = inter @ w_out + b_out (dense, no atomics) --
// m97 structure, 128x128 tile. A-MAJOR grid (g-major): the 8 nb-blocks sharing
// one A-panel co-reside per XCD (keeps the FETCH win). grid 576, ~528 active.
__global__ void __launch_bounds__(256, 3) ffn2_kernel(
    const unsigned short* __restrict__ inter,
    const unsigned short* __restrict__ wout_t,  // [E][H][I]
    const float* __restrict__ b_out,            // [E][H]
    const int* __restrict__ counts,
    float* __restrict__ y) {                    // [slot][H]
  const int logical = xcd_swz(blockIdx.x, RB128 * 8);
  const int g = logical >> 3;      // consecutive logicals share A panel
  const int nb = logical & 7;
  int e, mb, cnt;
  if (!rb_lookup(counts, g, &e, &mb, &cnt)) return;
  (void)mb;

  __shared__ char smem[32768];  // A 16KB | B 16KB

  const int tid = threadIdx.x;
  const int wave = tid >> 6, lane = tid & 63;
  const int wr = wave >> 1, wn = wave & 1;  // 2M x 2N
  const int l16 = lane & 15, l4 = lane >> 4;
  const unsigned short* Bbase =
      wout_t + (size_t)e * H_DIM * I_DIM + (size_t)(nb * 128) * I_DIM;
  const size_t rowbase = (size_t)g * 128;

  f32x4 acc[4][4] = {};

  const int NK = I_DIM / 64;  // 64
  for (int kt = 0; kt < NK; ++kt) {
    __syncthreads();
#pragma unroll
    for (int it = 0; it < 4; ++it) {
      int id = it * 256 + tid;
      int r = id >> 3;
      int cs = (id & 7) ^ (r & 7);
      lds_load16(inter + (rowbase + r) * (size_t)I_DIM + kt * 64 + cs * 8,
                 smem + id * 16);
      lds_load16(Bbase + (size_t)r * I_DIM + kt * 64 + cs * 8,
                 smem + 16384 + id * 16);
    }
    __syncthreads();
#pragma unroll
    for (int kk = 0; kk < 2; ++kk) {
      bf16x8 af[4], bv[4];
#pragma unroll
      for (int m = 0; m < 4; ++m)
        af[m] = *lds_frag(smem, wr * 64 + m * 16 + l16, kk * 4 + l4);
#pragma unroll
      for (int n = 0; n < 4; ++n)
        bv[n] = *lds_frag(smem + 16384, wn * 64 + n * 16 + l16, kk * 4 + l4);
#pragma unroll
      for (int m = 0; m < 4; ++m)
#pragma unroll
        for (int n = 0; n < 4; ++n)
          acc[m][n] =
              __builtin_amdgcn_mfma_f32_16x16x32_bf16(af[m], bv[n], acc[m][n], 0, 0, 0);
    }
  }

  // ---- epilogue: two 32-row passes through per-wave 8KB LDS slice ----
  __syncthreads();
  float* slice = (float*)(smem + wave * 8192);
  float bias[4];
#pragma unroll
  for (int n = 0; n < 4; ++n)
    bias[n] = b_out[e * H_DIM + nb * 128 + wn * 64 + n * 16 + l16];
#pragma unroll
  for (int p = 0; p < 2; ++p) {
#pragma unroll
    for (int mm = 0; mm < 2; ++mm) {
      int m = p * 2 + mm;
#pragma unroll
      for (int n = 0; n < 4; ++n) {
#pragma unroll
        for (int j = 0; j < 4; ++j) {
          slice[(mm * 16 + l4 * 4 + j) * 64 + n * 16 + l16] =
              acc[m][n][j] + bias[n];
        }
      }
    }
    __syncthreads();  // slice writes visible before cross-lane readback
#pragma unroll
    for (int it = 0; it < 8; ++it) {
      int row = it * 4 + (lane >> 4);      // 0..31
      int col = (lane & 15) * 4;           // 4 floats = 16B
      float4 v = *(const float4*)&slice[row * 64 + col];
      *(float4*)&y[(rowbase + wr * 64 + p * 32 + row) * (size_t)H_DIM +
                   nb * 128 + wn * 64 + col] = v;
    }
    __syncthreads();  // readback done before next pass overwrites slice
  }
}

// ---------------- combine: out[t] = w0*y[slot0] + w1*y[slot1] ---------------
__global__ void __launch_bounds__(256) combine_kernel(
    const float* __restrict__ y, const int* __restrict__ counts,
    const int* __restrict__ se, const float* __restrict__ wtok,
    float* __restrict__ out) {
  const int t = blockIdx.x;
  int poff[NE];
  int run = 0;
#pragma unroll
  for (int e = 0; e < NE; ++e) {
    poff[e] = run;
    run += (counts[e] + 127) & ~127;  // must match 128-row block padding
  }
  int c0 = se[2 * t], c1 = se[2 * t + 1];
  float w0 = wtok[2 * t], w1 = wtok[2 * t + 1];
  const float* y0 = y + (size_t)(poff[c0 >> 20] + (c0 & 0xFFFFF)) * H_DIM;
  const float* y1 = y + (size_t)(poff[c1 >> 20] + (c1 & 0xFFFFF)) * H_DIM;
  int h = threadIdx.x * 4;
  float4 a = *reinterpret_cast<const float4*>(y0 + h);
  float4 b = *reinterpret_cast<const float4*>(y1 + h);
  float4 o;
  o.x = w0 * a.x + w1 * b.x;
  o.y = w0 * a.y + w1 * b.y;
  o.z = w0 * a.z + w1 * b.z;
  o.w = w0 * a.w + w1 * b.w;
  *reinterpret_cast<float4*>(out + (size_t)t * H_DIM + h) = o;
}

extern "C" void kernel_launch(void* const* d_in, const int* in_sizes, int n_in,
                              void* d_out, int out_size, void* d_ws, size_t ws_size,
                              hipStream_t stream) {
  const float* x     = (const float*)d_in[0];
  const float* rw    = (const float*)d_in[1];
  const float* w_in  = (const float*)d_in[2];
  const float* b_in  = (const float*)d_in[3];
  const float* w_out = (const float*)d_in[4];
  const float* b_out = (const float*)d_in[5];
  float* out = (float*)d_out;

  char* ws = (char*)d_ws;
  size_t off = 0;
  auto alloc = [&](size_t bytes) {
    char* p = ws + off;
    off = (off + bytes + 255) & ~(size_t)255;
    return p;
  };
  int* counts            = (int*)alloc(NE * 4);
  int* perm              = (int*)alloc((size_t)NE * CAP * 4);
  int* se                = (int*)alloc((size_t)T_TOK * 2 * 4);
  float* wtok            = (float*)alloc((size_t)T_TOK * 2 * 4);
  unsigned short* xb     = (unsigned short*)alloc((size_t)T_TOK * H_DIM * 2);
  unsigned short* win_t  = (unsigned short*)alloc((size_t)NE * H_DIM * I_DIM * 2);
  unsigned short* wout_t = (unsigned short*)alloc((size_t)NE * H_DIM * I_DIM * 2);
  unsigned short* inter  = (unsigned short*)alloc((size_t)(T_TOK * 2 + NE * 256) * I_DIM * 2);
  // y overlays ONLY win_t (dead after ffn1; rewritten by transpose before the
  // next ffn1): need <= 9216*1024*4 = 37.7MB <= 64MB
  float* y = (float*)win_t;
  if (off > ws_size) return;  // ws too small -> visible correctness failure

  hipMemsetAsync(counts, 0, NE * sizeof(int), stream);

  router_kernel<<<T_TOK, 64, 0, stream>>>(x, rw, counts, perm, se, wtok);
  convert_x_kernel<<<(T_TOK * H_DIM / 4) / 256, 256, 0, stream>>>(x, xb);
  transpose_conv_kernel<<<dim3(I_DIM / 64, H_DIM / 64, NE), 256, 0, stream>>>(
      w_in, win_t, H_DIM, I_DIM);
  transpose_conv_kernel<<<dim3(H_DIM / 64, I_DIM / 64, NE), 256, 0, stream>>>(
      w_out, wout_t, I_DIM, H_DIM);
  ffn1_kernel<<<32 * RB128, 256, 0, stream>>>(xb, win_t, b_in, counts, perm,
                                              inter);
  ffn2_kernel<<<RB128 * 8, 256, 0, stream>>>(inter, wout_t, b_out, counts, y);
  combine_kernel<<<T_TOK, 256, 0, stream>>>(y, counts, se, wtok, out);
}